// Round 6
// baseline (581.398 us; speedup 1.0000x reference)
//
#include <hip/hip_runtime.h>

#define IN_CH 128
#define HID 64
#define NSHARD 8
#define SCAN_CHUNK 8192  // elements per scan block (256 threads x 8 int4)

// ---------------- phase A: sharded histogram + per-edge rank ----------------
// shard g = edge slice [g*SL,(g+1)*SL). cnt2[g*N+d] counts edges of shard g
// with dst d. atomicAdd's RETURN is the edge's rank within (g,d) -> uint16.
__global__ void k_hist(const int* __restrict__ dst, int* __restrict__ cnt2,
                       unsigned short* __restrict__ rank16, int E, int N, int SL) {
    int e = blockIdx.x * blockDim.x + threadIdx.x;
    if (e >= E) return;
    int d = __builtin_nontemporal_load(dst + e);
    int g = e / SL;
    int old = atomicAdd(&cnt2[g * N + d], 1);
    rank16[e] = (unsigned short)old;
}

// ---------------- dinv from raw counts (before in-place scan) ----------------
__global__ void k_dinv(const int* __restrict__ cnt2, float* __restrict__ dinv, int N) {
    int d = blockIdx.x * blockDim.x + threadIdx.x;
    if (d >= N) return;
    int deg = 1;  // self-loop
#pragma unroll
    for (int g = 0; g < NSHARD; ++g) deg += cnt2[g * N + d];
    dinv[d] = rsqrtf((float)deg);
}

// ---------------- phase B: multi-block exclusive scan (in place) ----------------
__global__ __launch_bounds__(256) void k_scan_blocksum(const int* __restrict__ a,
                                                       int* __restrict__ bsum, int M) {
    int t = threadIdx.x;
    int base = blockIdx.x * SCAN_CHUNK + t * 32;
    int s = 0;
#pragma unroll
    for (int q = 0; q < 8; ++q) {
        int b = base + q * 4;
        if (b + 3 < M) {
            int4 v = *(const int4*)(a + b);
            s += v.x + v.y + v.z + v.w;
        } else {
            for (int i = 0; i < 4; ++i) if (b + i < M) s += a[b + i];
        }
    }
#pragma unroll
    for (int off = 32; off; off >>= 1) s += __shfl_down(s, off);
    __shared__ int ws[4];
    if ((t & 63) == 0) ws[t >> 6] = s;
    __syncthreads();
    if (t == 0) bsum[blockIdx.x] = ws[0] + ws[1] + ws[2] + ws[3];
}

__global__ __launch_bounds__(128) void k_scan_bsums(int* __restrict__ bsum, int nb) {
    __shared__ int sh[128];
    int t = threadIdx.x;
    int v = (t < nb) ? bsum[t] : 0;
    sh[t] = v;
    __syncthreads();
    for (int off = 1; off < 128; off <<= 1) {
        int u = (t >= off) ? sh[t - off] : 0;
        __syncthreads();
        sh[t] += u;
        __syncthreads();
    }
    if (t < nb) bsum[t] = (t == 0) ? 0 : sh[t - 1];
}

// in-place: a[] (counts) -> exclusive prefix sums; a[M] = E
__global__ __launch_bounds__(256) void k_scan_apply(int* __restrict__ a,
                                                    const int* __restrict__ boff,
                                                    int M, int E) {
    int t = threadIdx.x;
    int base = blockIdx.x * SCAN_CHUNK + t * 32;
    int v[32];
    int tsum = 0;
#pragma unroll
    for (int q = 0; q < 8; ++q) {
        int b = base + q * 4;
        if (b + 3 < M) {
            int4 w = *(const int4*)(a + b);
            v[q * 4 + 0] = w.x; v[q * 4 + 1] = w.y; v[q * 4 + 2] = w.z; v[q * 4 + 3] = w.w;
        } else {
            for (int i = 0; i < 4; ++i) v[q * 4 + i] = (b + i < M) ? a[b + i] : 0;
        }
        tsum += v[q * 4] + v[q * 4 + 1] + v[q * 4 + 2] + v[q * 4 + 3];
    }
    __shared__ int sh[256];
    sh[t] = tsum;
    __syncthreads();
    for (int off = 1; off < 256; off <<= 1) {
        int u = (t >= off) ? sh[t - off] : 0;
        __syncthreads();
        sh[t] += u;
        __syncthreads();
    }
    int run = ((t == 0) ? 0 : sh[t - 1]) + boff[blockIdx.x];
#pragma unroll
    for (int q = 0; q < 8; ++q) {
        int b = base + q * 4;
        int o0 = run;            run += v[q * 4 + 0];
        int o1 = run;            run += v[q * 4 + 1];
        int o2 = run;            run += v[q * 4 + 2];
        int o3 = run;            run += v[q * 4 + 3];
        if (b + 3 < M) { *(int4*)(a + b) = make_int4(o0, o1, o2, o3); }
        else {
            if (b     < M) a[b]     = o0;
            if (b + 1 < M) a[b + 1] = o1;
            if (b + 2 < M) a[b + 2] = o2;
            if (b + 3 < M) a[b + 3] = o3;
        }
    }
    if (blockIdx.x == 0 && t == 0) a[M] = E;
}

// ---------------- phase C: atomic-free bucket, XCD-local writes ----------------
// Blocks with blockIdx&7==g read ONLY slice g (once, nt) and write ONLY shard
// g's contiguous esorted region: full-line writebacks from one XCD's L2.
__global__ __launch_bounds__(256) void k_bucket(const int* __restrict__ src,
                                                const int* __restrict__ dst,
                                                const unsigned short* __restrict__ rank16,
                                                const int* __restrict__ rowptr2,
                                                int* __restrict__ esorted,
                                                int E, int N, int SL) {
    const int grp = blockIdx.x & 7;
    const int blk = blockIdx.x >> 3;
    const int stride = (gridDim.x >> 3) * 256;
    const int lo = grp * SL;
    const int hi = min(E, lo + SL);
    const int* rpg = rowptr2 + grp * N;
    for (int e = lo + blk * 256 + threadIdx.x; e < hi; e += stride) {
        int d = __builtin_nontemporal_load(dst + e);
        int s = __builtin_nontemporal_load(src + e);
        int r = __builtin_nontemporal_load(rank16 + e);
        esorted[rpg[d] + r] = s;
    }
}

// ---------------- layer 1 GEMM: hp1 = dinv * (x @ W1) ----------------
__global__ __launch_bounds__(256) void k_gemm1(const float* __restrict__ x,
                                               const float* __restrict__ W1,
                                               const float* __restrict__ dinv,
                                               float* __restrict__ hp1, int N) {
    __shared__ float sW[IN_CH * HID];
    __shared__ float sx[16 * IN_CH];
    const int tid = threadIdx.x;
    const int node0 = blockIdx.x * 16;

    {
        const float4* g = (const float4*)W1;
        float4* s = (float4*)sW;
        for (int i = tid; i < IN_CH * HID / 4; i += 256) s[i] = g[i];
    }
    {
        const float4* g = (const float4*)(x + (size_t)node0 * IN_CH);
        float4* s = (float4*)sx;
        for (int i = tid; i < 16 * IN_CH / 4; i += 256) s[i] = g[i];
    }
    __syncthreads();

    const int k  = tid & 63;
    const int n0 = tid >> 6;  // 0..3
    float a0 = 0.f, a1 = 0.f, a2 = 0.f, a3 = 0.f;
#pragma unroll 8
    for (int j = 0; j < IN_CH; ++j) {
        float w = sW[j * HID + k];
        a0 = fmaf(sx[(n0     ) * IN_CH + j], w, a0);
        a1 = fmaf(sx[(n0 +  4) * IN_CH + j], w, a1);
        a2 = fmaf(sx[(n0 +  8) * IN_CH + j], w, a2);
        a3 = fmaf(sx[(n0 + 12) * IN_CH + j], w, a3);
    }
    hp1[(size_t)(node0 + n0     ) * HID + k] = a0 * dinv[node0 + n0];
    hp1[(size_t)(node0 + n0 +  4) * HID + k] = a1 * dinv[node0 + n0 + 4];
    hp1[(size_t)(node0 + n0 +  8) * HID + k] = a2 * dinv[node0 + n0 + 8];
    hp1[(size_t)(node0 + n0 + 12) * HID + k] = a3 * dinv[node0 + n0 + 12];
}

// ---- layer 1 aggregate + relu + bias + layer 2 projection, fused ----
// One wave per node, lane k = dim k. The node's edges live in 8 shard
// segments; walk them as 8 interleaved streams -> 8 independent gathers in
// flight per wave (keeps R4's MLP with the sharded CSR).
__global__ __launch_bounds__(256) void k_agg1(const int* __restrict__ rowptr2,
                                              const int* __restrict__ esorted,
                                              const float* __restrict__ hp1,
                                              const float* __restrict__ dinv,
                                              const float* __restrict__ b1,
                                              const float* __restrict__ W2,
                                              float* __restrict__ hp2, int N) {
    int wid = (blockIdx.x * blockDim.x + threadIdx.x) >> 6;
    if (wid >= N) return;
    int k = threadIdx.x & 63;
    int bs[NSHARD], es[NSHARD];
#pragma unroll
    for (int g = 0; g < NSHARD; ++g) {
        bs[g] = rowptr2[g * N + wid];
        es[g] = rowptr2[g * N + wid + 1];
    }
    float a[NSHARD];
#pragma unroll
    for (int g = 0; g < NSHARD; ++g) a[g] = 0.f;
    float self = hp1[(size_t)wid * HID + k];

    bool any = true;
    while (any) {
        any = false;
#pragma unroll
        for (int g = 0; g < NSHARD; ++g) {
            if (bs[g] < es[g]) {                    // wave-uniform condition
                int s = esorted[bs[g]++];
                a[g] += hp1[(size_t)s * HID + k];
                any = true;
            }
        }
    }
    float acc = self + ((a[0] + a[1]) + (a[2] + a[3])) + ((a[4] + a[5]) + (a[6] + a[7]));

    float dj = dinv[wid];
    float h = fmaxf(fmaf(dj, acc, b1[k]), 0.0f);
    float p0 = h * W2[k * 2 + 0];
    float p1 = h * W2[k * 2 + 1];
#pragma unroll
    for (int off = 32; off; off >>= 1) {
        p0 += __shfl_xor(p0, off);
        p1 += __shfl_xor(p1, off);
    }
    if (k == 0) {
        hp2[(size_t)wid * 2 + 0] = p0 * dj;
        hp2[(size_t)wid * 2 + 1] = p1 * dj;
    }
}

// ---------------- layer 2 aggregate + epilogue ----------------
// 8 lanes per node; lane l walks shard l's segment, shfl_xor reduce.
__global__ __launch_bounds__(256) void k_agg2(const int* __restrict__ rowptr2,
                                              const int* __restrict__ esorted,
                                              const float* __restrict__ hp2,
                                              const float* __restrict__ dinv,
                                              const float* __restrict__ b2,
                                              float* __restrict__ out, int N) {
    int gid = blockIdx.x * blockDim.x + threadIdx.x;
    int j = gid >> 3;
    if (j >= N) return;
    int l = gid & 7;
    int e  = rowptr2[l * N + j];
    int en = rowptr2[l * N + j + 1];
    float ax = 0.f, ay = 0.f;
    for (; e < en; ++e) {
        int s = esorted[e];
        float2 v = *(const float2*)(hp2 + (size_t)s * 2);
        ax += v.x;
        ay += v.y;
    }
#pragma unroll
    for (int off = 1; off < 8; off <<= 1) {
        ax += __shfl_xor(ax, off);
        ay += __shfl_xor(ay, off);
    }
    if (l == 0) {
        float2 self = *(const float2*)(hp2 + (size_t)j * 2);
        float dj = dinv[j];
        out[(size_t)j * 2 + 0] = fmaf(dj, ax + self.x, b2[0]);
        out[(size_t)j * 2 + 1] = fmaf(dj, ay + self.y, b2[1]);
    }
}

extern "C" void kernel_launch(void* const* d_in, const int* in_sizes, int n_in,
                              void* d_out, int out_size, void* d_ws, size_t ws_size,
                              hipStream_t stream) {
    const float* x  = (const float*)d_in[0];
    const int*   ei = (const int*)d_in[1];
    const float* W1 = (const float*)d_in[2];
    const float* b1 = (const float*)d_in[3];
    const float* W2 = (const float*)d_in[4];
    const float* b2 = (const float*)d_in[5];
    float* out = (float*)d_out;

    const int N = in_sizes[0] / IN_CH;   // 100000
    const int E = in_sizes[1] / 2;       // 3200000
    const int* src = ei;
    const int* dst = ei + E;
    const int SL = (E + NSHARD - 1) / NSHARD;            // 400000
    const int M  = NSHARD * N;                           // 800000
    const int NB = (M + SCAN_CHUNK - 1) / SCAN_CHUNK;    // 98 (<=128 required)

    char* ws = (char*)d_ws;
    size_t o = 0;
    auto carve = [&](size_t bytes) -> char* {
        char* p = ws + o;
        o = (o + bytes + 255) & ~(size_t)255;
        return p;
    };
    int*            rowptr2 = (int*)carve(((size_t)M + 1) * 4);  // counts -> scanned in place
    unsigned short* rank16  = (unsigned short*)carve((size_t)E * 2);
    float*          dinv    = (float*)carve((size_t)N * 4);
    int*            bsum    = (int*)carve(128 * 4);
    int*            esorted = (int*)carve((size_t)E * 4);          // 12.8 MB
    float*          hp1     = (float*)carve((size_t)N * HID * 4);  // 25.6 MB
    float*          hp2     = (float*)carve((size_t)N * 2 * 4);
    (void)ws_size;

    hipMemsetAsync(rowptr2, 0, (size_t)M * 4, stream);
    k_hist<<<(E + 255) / 256, 256, 0, stream>>>(dst, rowptr2, rank16, E, N, SL);
    k_dinv<<<(N + 255) / 256, 256, 0, stream>>>(rowptr2, dinv, N);
    k_scan_blocksum<<<NB, 256, 0, stream>>>(rowptr2, bsum, M);
    k_scan_bsums<<<1, 128, 0, stream>>>(bsum, NB);
    k_scan_apply<<<NB, 256, 0, stream>>>(rowptr2, bsum, M, E);
    k_bucket<<<2048, 256, 0, stream>>>(src, dst, rank16, rowptr2, esorted, E, N, SL);

    k_gemm1<<<(N + 15) / 16, 256, 0, stream>>>(x, W1, dinv, hp1, N);
    k_agg1<<<(unsigned)(((size_t)N * 64 + 255) / 256), 256, 0, stream>>>(
        rowptr2, esorted, hp1, dinv, b1, W2, hp2, N);
    k_agg2<<<(unsigned)(((size_t)N * 8 + 255) / 256), 256, 0, stream>>>(
        rowptr2, esorted, hp2, dinv, b2, out, N);
}

// Round 7
// 412.924 us; speedup vs baseline: 1.4080x; 1.4080x over previous
//
#include <hip/hip_runtime.h>

#define IN_CH 128
#define HID 64
#define SCAN_CHUNK 1024  // elements per scan block (256 threads x int4)

// ---------------- phase A: histogram of dst + per-edge rank ----------------
// atomicAdd's RETURN value is this edge's rank among same-dst edges (order
// nondeterministic -> esorted is a permutation within each row; sums invariant).
__global__ void k_hist(const int* __restrict__ dst, int* __restrict__ cnt,
                       unsigned short* __restrict__ rank16, int E) {
    int e = blockIdx.x * blockDim.x + threadIdx.x;
    if (e >= E) return;
    int d = __builtin_nontemporal_load(dst + e);
    int old = atomicAdd(&cnt[d], 1);
    rank16[e] = (unsigned short)old;
}

// ---------------- phase B: multi-block exclusive scan ----------------
__global__ __launch_bounds__(256) void k_scan_blocksum(const int* __restrict__ cnt,
                                                       int* __restrict__ bsum, int N) {
    int t = threadIdx.x;
    int base = blockIdx.x * SCAN_CHUNK + t * 4;
    int4 v = make_int4(0, 0, 0, 0);
    if (base + 3 < N) v = *(const int4*)(cnt + base);
    else {
        if (base     < N) v.x = cnt[base];
        if (base + 1 < N) v.y = cnt[base + 1];
        if (base + 2 < N) v.z = cnt[base + 2];
        if (base + 3 < N) v.w = cnt[base + 3];
    }
    int s = v.x + v.y + v.z + v.w;
#pragma unroll
    for (int off = 32; off; off >>= 1) s += __shfl_down(s, off);
    __shared__ int ws[4];
    if ((t & 63) == 0) ws[t >> 6] = s;
    __syncthreads();
    if (t == 0) bsum[blockIdx.x] = ws[0] + ws[1] + ws[2] + ws[3];
}

__global__ __launch_bounds__(128) void k_scan_bsums(int* __restrict__ bsum, int nb) {
    __shared__ int sh[128];
    int t = threadIdx.x;
    int v = (t < nb) ? bsum[t] : 0;
    sh[t] = v;
    __syncthreads();
    for (int off = 1; off < 128; off <<= 1) {
        int u = (t >= off) ? sh[t - off] : 0;
        __syncthreads();
        sh[t] += u;
        __syncthreads();
    }
    if (t < nb) bsum[t] = (t == 0) ? 0 : sh[t - 1];
}

// rowptr/dinv from counts (also keeps counts needed nowhere else afterwards)
__global__ __launch_bounds__(256) void k_scan_apply(const int* __restrict__ cnt,
                                                    const int* __restrict__ boff,
                                                    int* __restrict__ rowptr,
                                                    float* __restrict__ dinv,
                                                    int N, int E) {
    int t = threadIdx.x;
    int base = blockIdx.x * SCAN_CHUNK + t * 4;
    int4 v = make_int4(0, 0, 0, 0);
    if (base + 3 < N) v = *(const int4*)(cnt + base);
    else {
        if (base     < N) v.x = cnt[base];
        if (base + 1 < N) v.y = cnt[base + 1];
        if (base + 2 < N) v.z = cnt[base + 2];
        if (base + 3 < N) v.w = cnt[base + 3];
    }
    int tsum = v.x + v.y + v.z + v.w;
    __shared__ int sh[256];
    sh[t] = tsum;
    __syncthreads();
    for (int off = 1; off < 256; off <<= 1) {
        int u = (t >= off) ? sh[t - off] : 0;
        __syncthreads();
        sh[t] += u;
        __syncthreads();
    }
    int run = ((t == 0) ? 0 : sh[t - 1]) + boff[blockIdx.x];
    int p0 = run;
    int p1 = p0 + v.x;
    int p2 = p1 + v.y;
    int p3 = p2 + v.z;
    if (base < N) {
        rowptr[base] = p0; dinv[base] = rsqrtf(1.0f + (float)v.x);
    }
    if (base + 1 < N) {
        rowptr[base + 1] = p1; dinv[base + 1] = rsqrtf(1.0f + (float)v.y);
    }
    if (base + 2 < N) {
        rowptr[base + 2] = p2; dinv[base + 2] = rsqrtf(1.0f + (float)v.z);
    }
    if (base + 3 < N) {
        rowptr[base + 3] = p3; dinv[base + 3] = rsqrtf(1.0f + (float)v.w);
    }
    if (blockIdx.x == 0 && t == 0) rowptr[N] = E;
}

// ---------------- phase C: atomic-free bucket, XCD-partitioned writes --------
// pos = rowptr[d] + rank16[e] (unique, no atomics). Blocks only handle edges
// with (d>>7)&7 == blockIdx&7 so each esorted line is written by one XCD
// (full-line writebacks). Price: dst read 8x via nontemporal loads.
__global__ __launch_bounds__(256) void k_bucket(const int* __restrict__ src,
                                                const int* __restrict__ dst,
                                                const unsigned short* __restrict__ rank16,
                                                const int* __restrict__ rowptr,
                                                int* __restrict__ esorted, int E) {
    const int grp    = blockIdx.x & 7;
    const int blk    = blockIdx.x >> 3;
    const int stride = (gridDim.x >> 3) * 256;
    for (int e = blk * 256 + threadIdx.x; e < E; e += stride) {
        int d = __builtin_nontemporal_load(dst + e);
        if (((d >> 7) & 7) == grp) {
            int s = __builtin_nontemporal_load(src + e);
            int r = __builtin_nontemporal_load(rank16 + e);
            esorted[rowptr[d] + r] = s;
        }
    }
}

// ---------------- layer 1 GEMM: hp1 = dinv * (x @ W1) ----------------
__global__ __launch_bounds__(256) void k_gemm1(const float* __restrict__ x,
                                               const float* __restrict__ W1,
                                               const float* __restrict__ dinv,
                                               float* __restrict__ hp1, int N) {
    __shared__ float sW[IN_CH * HID];
    __shared__ float sx[16 * IN_CH];
    const int tid = threadIdx.x;
    const int node0 = blockIdx.x * 16;

    {
        const float4* g = (const float4*)W1;
        float4* s = (float4*)sW;
        for (int i = tid; i < IN_CH * HID / 4; i += 256) s[i] = g[i];
    }
    {
        const float4* g = (const float4*)(x + (size_t)node0 * IN_CH);
        float4* s = (float4*)sx;
        for (int i = tid; i < 16 * IN_CH / 4; i += 256) s[i] = g[i];
    }
    __syncthreads();

    const int k  = tid & 63;
    const int n0 = tid >> 6;  // 0..3
    float a0 = 0.f, a1 = 0.f, a2 = 0.f, a3 = 0.f;
#pragma unroll 8
    for (int j = 0; j < IN_CH; ++j) {
        float w = sW[j * HID + k];
        a0 = fmaf(sx[(n0     ) * IN_CH + j], w, a0);
        a1 = fmaf(sx[(n0 +  4) * IN_CH + j], w, a1);
        a2 = fmaf(sx[(n0 +  8) * IN_CH + j], w, a2);
        a3 = fmaf(sx[(n0 + 12) * IN_CH + j], w, a3);
    }
    hp1[(size_t)(node0 + n0     ) * HID + k] = a0 * dinv[node0 + n0];
    hp1[(size_t)(node0 + n0 +  4) * HID + k] = a1 * dinv[node0 + n0 + 4];
    hp1[(size_t)(node0 + n0 +  8) * HID + k] = a2 * dinv[node0 + n0 + 8];
    hp1[(size_t)(node0 + n0 + 12) * HID + k] = a3 * dinv[node0 + n0 + 12];
}

// ---- layer 1 aggregate + relu + bias + layer 2 projection, fused ----
// One wave per node, lane k = dim k; monolithic CSR row walked with 8-deep
// unroll (8 independent row-gathers in flight). R4-proven form.
__global__ __launch_bounds__(256) void k_agg1(const int* __restrict__ rowptr,
                                              const int* __restrict__ esorted,
                                              const float* __restrict__ hp1,
                                              const float* __restrict__ dinv,
                                              const float* __restrict__ b1,
                                              const float* __restrict__ W2,
                                              float* __restrict__ hp2, int N) {
    int wid = (blockIdx.x * blockDim.x + threadIdx.x) >> 6;
    if (wid >= N) return;
    int k = threadIdx.x & 63;
    int beg = rowptr[wid], end = rowptr[wid + 1];
    float a0 = hp1[(size_t)wid * HID + k];  // self-loop term
    float a1 = 0.f, a2 = 0.f, a3 = 0.f, a4 = 0.f, a5 = 0.f, a6 = 0.f, a7 = 0.f;
    int e = beg;
    for (; e + 7 < end; e += 8) {
        int s0 = esorted[e + 0], s1 = esorted[e + 1];
        int s2 = esorted[e + 2], s3 = esorted[e + 3];
        int s4 = esorted[e + 4], s5 = esorted[e + 5];
        int s6 = esorted[e + 6], s7 = esorted[e + 7];
        a0 += hp1[(size_t)s0 * HID + k];
        a1 += hp1[(size_t)s1 * HID + k];
        a2 += hp1[(size_t)s2 * HID + k];
        a3 += hp1[(size_t)s3 * HID + k];
        a4 += hp1[(size_t)s4 * HID + k];
        a5 += hp1[(size_t)s5 * HID + k];
        a6 += hp1[(size_t)s6 * HID + k];
        a7 += hp1[(size_t)s7 * HID + k];
    }
    for (; e < end; ++e) a0 += hp1[(size_t)esorted[e] * HID + k];
    float acc = ((a0 + a1) + (a2 + a3)) + ((a4 + a5) + (a6 + a7));

    float dj = dinv[wid];
    float h = fmaxf(fmaf(dj, acc, b1[k]), 0.0f);
    float p0 = h * W2[k * 2 + 0];
    float p1 = h * W2[k * 2 + 1];
#pragma unroll
    for (int off = 32; off; off >>= 1) {
        p0 += __shfl_xor(p0, off);
        p1 += __shfl_xor(p1, off);
    }
    if (k == 0) {
        hp2[(size_t)wid * 2 + 0] = p0 * dj;
        hp2[(size_t)wid * 2 + 1] = p1 * dj;
    }
}

// ---------------- layer 2 aggregate + epilogue ----------------
// 8 lanes per node (aligned group), strided edges, shfl_xor reduce.
__global__ __launch_bounds__(256) void k_agg2(const int* __restrict__ rowptr,
                                              const int* __restrict__ esorted,
                                              const float* __restrict__ hp2,
                                              const float* __restrict__ dinv,
                                              const float* __restrict__ b2,
                                              float* __restrict__ out, int N) {
    int gid = blockIdx.x * blockDim.x + threadIdx.x;
    int j = gid >> 3;
    if (j >= N) return;
    int l = gid & 7;
    int beg = rowptr[j], end = rowptr[j + 1];
    float ax = 0.f, ay = 0.f;
    for (int e = beg + l; e < end; e += 8) {
        int s = esorted[e];
        float2 v = *(const float2*)(hp2 + (size_t)s * 2);
        ax += v.x;
        ay += v.y;
    }
#pragma unroll
    for (int off = 1; off < 8; off <<= 1) {
        ax += __shfl_xor(ax, off);
        ay += __shfl_xor(ay, off);
    }
    if (l == 0) {
        float2 self = *(const float2*)(hp2 + (size_t)j * 2);
        float dj = dinv[j];
        out[(size_t)j * 2 + 0] = fmaf(dj, ax + self.x, b2[0]);
        out[(size_t)j * 2 + 1] = fmaf(dj, ay + self.y, b2[1]);
    }
}

extern "C" void kernel_launch(void* const* d_in, const int* in_sizes, int n_in,
                              void* d_out, int out_size, void* d_ws, size_t ws_size,
                              hipStream_t stream) {
    const float* x  = (const float*)d_in[0];
    const int*   ei = (const int*)d_in[1];
    const float* W1 = (const float*)d_in[2];
    const float* b1 = (const float*)d_in[3];
    const float* W2 = (const float*)d_in[4];
    const float* b2 = (const float*)d_in[5];
    float* out = (float*)d_out;

    const int N = in_sizes[0] / IN_CH;   // 100000
    const int E = in_sizes[1] / 2;       // 3200000
    const int* src = ei;
    const int* dst = ei + E;
    const int NB = (N + SCAN_CHUNK - 1) / SCAN_CHUNK;  // 98 (<=128 required)

    char* ws = (char*)d_ws;
    size_t o = 0;
    auto carve = [&](size_t bytes) -> char* {
        char* p = ws + o;
        o = (o + bytes + 255) & ~(size_t)255;
        return p;
    };
    int*            cnt     = (int*)carve((size_t)N * 4);
    int*            rowptr  = (int*)carve(((size_t)N + 1) * 4);
    float*          dinv    = (float*)carve((size_t)N * 4);
    int*            bsum    = (int*)carve(128 * 4);
    unsigned short* rank16  = (unsigned short*)carve((size_t)E * 2);  // 6.4 MB
    int*            esorted = (int*)carve((size_t)E * 4);             // 12.8 MB
    float*          hp1     = (float*)carve((size_t)N * HID * 4);     // 25.6 MB
    float*          hp2     = (float*)carve((size_t)N * 2 * 4);
    (void)ws_size;

    hipMemsetAsync(cnt, 0, (size_t)N * 4, stream);
    k_hist<<<(E + 255) / 256, 256, 0, stream>>>(dst, cnt, rank16, E);
    k_scan_blocksum<<<NB, 256, 0, stream>>>(cnt, bsum, N);
    k_scan_bsums<<<1, 128, 0, stream>>>(bsum, NB);
    k_scan_apply<<<NB, 256, 0, stream>>>(cnt, bsum, rowptr, dinv, N, E);
    k_bucket<<<4096, 256, 0, stream>>>(src, dst, rank16, rowptr, esorted, E);

    k_gemm1<<<(N + 15) / 16, 256, 0, stream>>>(x, W1, dinv, hp1, N);
    k_agg1<<<(unsigned)(((size_t)N * 64 + 255) / 256), 256, 0, stream>>>(
        rowptr, esorted, hp1, dinv, b1, W2, hp2, N);
    k_agg2<<<(unsigned)(((size_t)N * 8 + 255) / 256), 256, 0, stream>>>(
        rowptr, esorted, hp2, dinv, b2, out, N);
}

// Round 8
// 286.811 us; speedup vs baseline: 2.0271x; 1.4397x over previous
//
#include <hip/hip_runtime.h>

#define IN_CH 128
#define HID 64
#define CHUNK1 16384   // edges per p1 block
#define GBITS 8        // 256 nodes per group
#define SCAN_CHUNK 8192

// ---------- p1 count: LDS histogram of dst>>8 per edge-chunk ----------
__global__ __launch_bounds__(256) void k_p1count(const int* __restrict__ dst,
                                                 int* __restrict__ C,
                                                 int E, int G, int NB1) {
    __shared__ int lcnt[512];
    int t = threadIdx.x;
    for (int i = t; i < G; i += 256) lcnt[i] = 0;
    __syncthreads();
    int lo = blockIdx.x * CHUNK1;
    int hi = min(E, lo + CHUNK1);
    for (int e = lo + t; e < hi; e += 256) {
        int d = __builtin_nontemporal_load(dst + e);
        atomicAdd(&lcnt[d >> GBITS], 1);
    }
    __syncthreads();
    for (int g = t; g < G; g += 256) C[(size_t)g * NB1 + blockIdx.x] = lcnt[g];
}

// ---------- multi-block exclusive scan, in place (R5-verified) ----------
__global__ __launch_bounds__(256) void k_scan_blocksum(const int* __restrict__ a,
                                                       int* __restrict__ bsum, int M) {
    int t = threadIdx.x;
    int base = blockIdx.x * SCAN_CHUNK + t * 32;
    int s = 0;
#pragma unroll
    for (int q = 0; q < 8; ++q) {
        int b = base + q * 4;
        if (b + 3 < M) {
            int4 v = *(const int4*)(a + b);
            s += v.x + v.y + v.z + v.w;
        } else {
            for (int i = 0; i < 4; ++i) if (b + i < M) s += a[b + i];
        }
    }
#pragma unroll
    for (int off = 32; off; off >>= 1) s += __shfl_down(s, off);
    __shared__ int ws[4];
    if ((t & 63) == 0) ws[t >> 6] = s;
    __syncthreads();
    if (t == 0) bsum[blockIdx.x] = ws[0] + ws[1] + ws[2] + ws[3];
}

__global__ __launch_bounds__(128) void k_scan_bsums(int* __restrict__ bsum, int nb) {
    __shared__ int sh[128];
    int t = threadIdx.x;
    int v = (t < nb) ? bsum[t] : 0;
    sh[t] = v;
    __syncthreads();
    for (int off = 1; off < 128; off <<= 1) {
        int u = (t >= off) ? sh[t - off] : 0;
        __syncthreads();
        sh[t] += u;
        __syncthreads();
    }
    if (t < nb) bsum[t] = (t == 0) ? 0 : sh[t - 1];
}

__global__ __launch_bounds__(256) void k_scan_apply(int* __restrict__ a,
                                                    const int* __restrict__ boff,
                                                    int M, int E) {
    int t = threadIdx.x;
    int base = blockIdx.x * SCAN_CHUNK + t * 32;
    int v[32];
    int tsum = 0;
#pragma unroll
    for (int q = 0; q < 8; ++q) {
        int b = base + q * 4;
        if (b + 3 < M) {
            int4 w = *(const int4*)(a + b);
            v[q * 4 + 0] = w.x; v[q * 4 + 1] = w.y; v[q * 4 + 2] = w.z; v[q * 4 + 3] = w.w;
        } else {
            for (int i = 0; i < 4; ++i) v[q * 4 + i] = (b + i < M) ? a[b + i] : 0;
        }
        tsum += v[q * 4] + v[q * 4 + 1] + v[q * 4 + 2] + v[q * 4 + 3];
    }
    __shared__ int sh[256];
    sh[t] = tsum;
    __syncthreads();
    for (int off = 1; off < 256; off <<= 1) {
        int u = (t >= off) ? sh[t - off] : 0;
        __syncthreads();
        sh[t] += u;
        __syncthreads();
    }
    int run = ((t == 0) ? 0 : sh[t - 1]) + boff[blockIdx.x];
#pragma unroll
    for (int q = 0; q < 8; ++q) {
        int b = base + q * 4;
        int o0 = run;            run += v[q * 4 + 0];
        int o1 = run;            run += v[q * 4 + 1];
        int o2 = run;            run += v[q * 4 + 2];
        int o3 = run;            run += v[q * 4 + 3];
        if (b + 3 < M) { *(int4*)(a + b) = make_int4(o0, o1, o2, o3); }
        else {
            if (b     < M) a[b]     = o0;
            if (b + 1 < M) a[b + 1] = o1;
            if (b + 2 < M) a[b + 2] = o2;
            if (b + 3 < M) a[b + 3] = o3;
        }
    }
    if (blockIdx.x == 0 && t == 0) a[M] = E;
}

// ---------- p1 scatter: edges -> group-contiguous part[], LDS cursors ----------
__global__ __launch_bounds__(256) void k_p1scat(const int* __restrict__ src,
                                                const int* __restrict__ dst,
                                                const int* __restrict__ S,
                                                unsigned int* __restrict__ part,
                                                int E, int G, int NB1) {
    __shared__ int lcur[512];
    int t = threadIdx.x;
    for (int g = t; g < G; g += 256) lcur[g] = S[(size_t)g * NB1 + blockIdx.x];
    __syncthreads();
    int lo = blockIdx.x * CHUNK1;
    int hi = min(E, lo + CHUNK1);
    for (int e = lo + t; e < hi; e += 256) {
        int d = __builtin_nontemporal_load(dst + e);
        int s = __builtin_nontemporal_load(src + e);
        int pos = atomicAdd(&lcur[d >> GBITS], 1);
        part[pos] = ((unsigned)s << GBITS) | (unsigned)(d & ((1 << GBITS) - 1));
    }
}

// ---------- p2: per-group fine CSR in LDS -> rowptr/dinv/esorted ----------
__global__ __launch_bounds__(256) void k_p2(const unsigned int* __restrict__ part,
                                            const int* __restrict__ S,
                                            int* __restrict__ rowptr,
                                            float* __restrict__ dinv,
                                            int* __restrict__ esorted,
                                            int E, int N, int G, int NB1) {
    __shared__ int lcnt[256], lpre[256], lcur[256];
    int t = threadIdx.x;
    int g = blockIdx.x;
    int base = S[(size_t)g * NB1];
    int end  = (g == G - 1) ? E : S[(size_t)(g + 1) * NB1];
    lcnt[t] = 0;
    __syncthreads();
    for (int i = base + t; i < end; i += 256) {
        unsigned p = part[i];
        atomicAdd(&lcnt[p & 255], 1);
    }
    __syncthreads();
    int v = lcnt[t];
    lpre[t] = v;
    __syncthreads();
    for (int off = 1; off < 256; off <<= 1) {
        int u = (t >= off) ? lpre[t - off] : 0;
        __syncthreads();
        lpre[t] += u;
        __syncthreads();
    }
    int excl = (t == 0) ? 0 : lpre[t - 1];
    lcur[t] = base + excl;                       // global cursor
    int node = (g << GBITS) + t;
    if (node < N) {
        rowptr[node] = base + excl;
        dinv[node] = rsqrtf(1.0f + (float)v);
    }
    if (g == 0 && t == 0) rowptr[N] = E;
    __syncthreads();
    for (int i = base + t; i < end; i += 256) {
        unsigned p = part[i];
        int pos = atomicAdd(&lcur[p & 255], 1);
        esorted[pos] = (int)(p >> GBITS);
    }
}

// ---------------- layer 1 GEMM: hp1 = dinv * (x @ W1) ----------------
__global__ __launch_bounds__(256) void k_gemm1(const float* __restrict__ x,
                                               const float* __restrict__ W1,
                                               const float* __restrict__ dinv,
                                               float* __restrict__ hp1, int N) {
    __shared__ float sW[IN_CH * HID];
    __shared__ float sx[16 * IN_CH];
    const int tid = threadIdx.x;
    const int node0 = blockIdx.x * 16;

    {
        const float4* g = (const float4*)W1;
        float4* s = (float4*)sW;
        for (int i = tid; i < IN_CH * HID / 4; i += 256) s[i] = g[i];
    }
    {
        const float4* g = (const float4*)(x + (size_t)node0 * IN_CH);
        float4* s = (float4*)sx;
        for (int i = tid; i < 16 * IN_CH / 4; i += 256) s[i] = g[i];
    }
    __syncthreads();

    const int k  = tid & 63;
    const int n0 = tid >> 6;  // 0..3
    float a0 = 0.f, a1 = 0.f, a2 = 0.f, a3 = 0.f;
#pragma unroll 8
    for (int j = 0; j < IN_CH; ++j) {
        float w = sW[j * HID + k];
        a0 = fmaf(sx[(n0     ) * IN_CH + j], w, a0);
        a1 = fmaf(sx[(n0 +  4) * IN_CH + j], w, a1);
        a2 = fmaf(sx[(n0 +  8) * IN_CH + j], w, a2);
        a3 = fmaf(sx[(n0 + 12) * IN_CH + j], w, a3);
    }
    hp1[(size_t)(node0 + n0     ) * HID + k] = a0 * dinv[node0 + n0];
    hp1[(size_t)(node0 + n0 +  4) * HID + k] = a1 * dinv[node0 + n0 + 4];
    hp1[(size_t)(node0 + n0 +  8) * HID + k] = a2 * dinv[node0 + n0 + 8];
    hp1[(size_t)(node0 + n0 + 12) * HID + k] = a3 * dinv[node0 + n0 + 12];
}

// ---- layer 1 aggregate + relu + bias + layer 2 projection, fused ----
__global__ __launch_bounds__(256) void k_agg1(const int* __restrict__ rowptr,
                                              const int* __restrict__ esorted,
                                              const float* __restrict__ hp1,
                                              const float* __restrict__ dinv,
                                              const float* __restrict__ b1,
                                              const float* __restrict__ W2,
                                              float* __restrict__ hp2, int N) {
    int wid = (blockIdx.x * blockDim.x + threadIdx.x) >> 6;
    if (wid >= N) return;
    int k = threadIdx.x & 63;
    int beg = rowptr[wid], end = rowptr[wid + 1];
    float a0 = hp1[(size_t)wid * HID + k];  // self-loop term
    float a1 = 0.f, a2 = 0.f, a3 = 0.f, a4 = 0.f, a5 = 0.f, a6 = 0.f, a7 = 0.f;
    int e = beg;
    for (; e + 7 < end; e += 8) {
        int s0 = esorted[e + 0], s1 = esorted[e + 1];
        int s2 = esorted[e + 2], s3 = esorted[e + 3];
        int s4 = esorted[e + 4], s5 = esorted[e + 5];
        int s6 = esorted[e + 6], s7 = esorted[e + 7];
        a0 += hp1[(size_t)s0 * HID + k];
        a1 += hp1[(size_t)s1 * HID + k];
        a2 += hp1[(size_t)s2 * HID + k];
        a3 += hp1[(size_t)s3 * HID + k];
        a4 += hp1[(size_t)s4 * HID + k];
        a5 += hp1[(size_t)s5 * HID + k];
        a6 += hp1[(size_t)s6 * HID + k];
        a7 += hp1[(size_t)s7 * HID + k];
    }
    for (; e < end; ++e) a0 += hp1[(size_t)esorted[e] * HID + k];
    float acc = ((a0 + a1) + (a2 + a3)) + ((a4 + a5) + (a6 + a7));

    float dj = dinv[wid];
    float h = fmaxf(fmaf(dj, acc, b1[k]), 0.0f);
    float p0 = h * W2[k * 2 + 0];
    float p1 = h * W2[k * 2 + 1];
#pragma unroll
    for (int off = 32; off; off >>= 1) {
        p0 += __shfl_xor(p0, off);
        p1 += __shfl_xor(p1, off);
    }
    if (k == 0) {
        hp2[(size_t)wid * 2 + 0] = p0 * dj;
        hp2[(size_t)wid * 2 + 1] = p1 * dj;
    }
}

// ---------------- layer 2 aggregate + epilogue ----------------
__global__ __launch_bounds__(256) void k_agg2(const int* __restrict__ rowptr,
                                              const int* __restrict__ esorted,
                                              const float* __restrict__ hp2,
                                              const float* __restrict__ dinv,
                                              const float* __restrict__ b2,
                                              float* __restrict__ out, int N) {
    int gid = blockIdx.x * blockDim.x + threadIdx.x;
    int j = gid >> 3;
    if (j >= N) return;
    int l = gid & 7;
    int beg = rowptr[j], end = rowptr[j + 1];
    float ax = 0.f, ay = 0.f;
    for (int e = beg + l; e < end; e += 8) {
        int s = esorted[e];
        float2 v = *(const float2*)(hp2 + (size_t)s * 2);
        ax += v.x;
        ay += v.y;
    }
#pragma unroll
    for (int off = 1; off < 8; off <<= 1) {
        ax += __shfl_xor(ax, off);
        ay += __shfl_xor(ay, off);
    }
    if (l == 0) {
        float2 self = *(const float2*)(hp2 + (size_t)j * 2);
        float dj = dinv[j];
        out[(size_t)j * 2 + 0] = fmaf(dj, ax + self.x, b2[0]);
        out[(size_t)j * 2 + 1] = fmaf(dj, ay + self.y, b2[1]);
    }
}

extern "C" void kernel_launch(void* const* d_in, const int* in_sizes, int n_in,
                              void* d_out, int out_size, void* d_ws, size_t ws_size,
                              hipStream_t stream) {
    const float* x  = (const float*)d_in[0];
    const int*   ei = (const int*)d_in[1];
    const float* W1 = (const float*)d_in[2];
    const float* b1 = (const float*)d_in[3];
    const float* W2 = (const float*)d_in[4];
    const float* b2 = (const float*)d_in[5];
    float* out = (float*)d_out;

    const int N = in_sizes[0] / IN_CH;   // 100000
    const int E = in_sizes[1] / 2;       // 3200000
    const int* src = ei;
    const int* dst = ei + E;

    const int G   = (N + 255) >> GBITS;             // 391 groups of 256 nodes
    const int NB1 = (E + CHUNK1 - 1) / CHUNK1;      // 196 p1 blocks
    const int M   = G * NB1;                        // 76636 counts
    const int NBs = (M + SCAN_CHUNK - 1) / SCAN_CHUNK;  // 10 (<=128 required)

    char* ws = (char*)d_ws;
    size_t o = 0;
    auto carve = [&](size_t bytes) -> char* {
        char* p = ws + o;
        o = (o + bytes + 255) & ~(size_t)255;
        return p;
    };
    int*          S       = (int*)carve(((size_t)M + 1) * 4);       // counts -> scanned
    unsigned int* part    = (unsigned int*)carve((size_t)E * 4);    // 12.8 MB
    int*          rowptr  = (int*)carve(((size_t)N + 1) * 4);
    float*        dinv    = (float*)carve((size_t)N * 4);
    int*          bsum    = (int*)carve(128 * 4);
    int*          esorted = (int*)carve((size_t)E * 4);             // 12.8 MB
    float*        hp1     = (float*)carve((size_t)N * HID * 4);     // 25.6 MB
    float*        hp2     = (float*)carve((size_t)N * 2 * 4);
    (void)ws_size;

    k_p1count<<<NB1, 256, 0, stream>>>(dst, S, E, G, NB1);
    k_scan_blocksum<<<NBs, 256, 0, stream>>>(S, bsum, M);
    k_scan_bsums<<<1, 128, 0, stream>>>(bsum, NBs);
    k_scan_apply<<<NBs, 256, 0, stream>>>(S, bsum, M, E);
    k_p1scat<<<NB1, 256, 0, stream>>>(src, dst, S, part, E, G, NB1);
    k_p2<<<G, 256, 0, stream>>>(part, S, rowptr, dinv, esorted, E, N, G, NB1);

    k_gemm1<<<(N + 15) / 16, 256, 0, stream>>>(x, W1, dinv, hp1, N);
    k_agg1<<<(unsigned)(((size_t)N * 64 + 255) / 256), 256, 0, stream>>>(
        rowptr, esorted, hp1, dinv, b1, W2, hp2, N);
    k_agg2<<<(unsigned)(((size_t)N * 8 + 255) / 256), 256, 0, stream>>>(
        rowptr, esorted, hp2, dinv, b2, out, N);
}

// Round 9
// 253.772 us; speedup vs baseline: 2.2910x; 1.1302x over previous
//
#include <hip/hip_runtime.h>
#include <hip/hip_fp16.h>

#define IN_CH 128
#define HID 64
#define CHUNK1 16384   // edges per p1 block
#define GBITS 8        // 256 nodes per group
#define SCAN_CHUNK 8192

// ---------- p1 count: LDS histogram of dst>>8 per edge-chunk ----------
__global__ __launch_bounds__(256) void k_p1count(const int* __restrict__ dst,
                                                 int* __restrict__ C,
                                                 int E, int G, int NB1) {
    __shared__ int lcnt[512];
    int t = threadIdx.x;
    for (int i = t; i < G; i += 256) lcnt[i] = 0;
    __syncthreads();
    int lo = blockIdx.x * CHUNK1;
    int hi = min(E, lo + CHUNK1);
    for (int e = lo + t; e < hi; e += 256) {
        int d = __builtin_nontemporal_load(dst + e);
        atomicAdd(&lcnt[d >> GBITS], 1);
    }
    __syncthreads();
    for (int g = t; g < G; g += 256) C[(size_t)g * NB1 + blockIdx.x] = lcnt[g];
}

// ---------- multi-block exclusive scan, in place (R5-verified) ----------
__global__ __launch_bounds__(256) void k_scan_blocksum(const int* __restrict__ a,
                                                       int* __restrict__ bsum, int M) {
    int t = threadIdx.x;
    int base = blockIdx.x * SCAN_CHUNK + t * 32;
    int s = 0;
#pragma unroll
    for (int q = 0; q < 8; ++q) {
        int b = base + q * 4;
        if (b + 3 < M) {
            int4 v = *(const int4*)(a + b);
            s += v.x + v.y + v.z + v.w;
        } else {
            for (int i = 0; i < 4; ++i) if (b + i < M) s += a[b + i];
        }
    }
#pragma unroll
    for (int off = 32; off; off >>= 1) s += __shfl_down(s, off);
    __shared__ int ws[4];
    if ((t & 63) == 0) ws[t >> 6] = s;
    __syncthreads();
    if (t == 0) bsum[blockIdx.x] = ws[0] + ws[1] + ws[2] + ws[3];
}

__global__ __launch_bounds__(128) void k_scan_bsums(int* __restrict__ bsum, int nb) {
    __shared__ int sh[128];
    int t = threadIdx.x;
    int v = (t < nb) ? bsum[t] : 0;
    sh[t] = v;
    __syncthreads();
    for (int off = 1; off < 128; off <<= 1) {
        int u = (t >= off) ? sh[t - off] : 0;
        __syncthreads();
        sh[t] += u;
        __syncthreads();
    }
    if (t < nb) bsum[t] = (t == 0) ? 0 : sh[t - 1];
}

__global__ __launch_bounds__(256) void k_scan_apply(int* __restrict__ a,
                                                    const int* __restrict__ boff,
                                                    int M, int E) {
    int t = threadIdx.x;
    int base = blockIdx.x * SCAN_CHUNK + t * 32;
    int v[32];
    int tsum = 0;
#pragma unroll
    for (int q = 0; q < 8; ++q) {
        int b = base + q * 4;
        if (b + 3 < M) {
            int4 w = *(const int4*)(a + b);
            v[q * 4 + 0] = w.x; v[q * 4 + 1] = w.y; v[q * 4 + 2] = w.z; v[q * 4 + 3] = w.w;
        } else {
            for (int i = 0; i < 4; ++i) v[q * 4 + i] = (b + i < M) ? a[b + i] : 0;
        }
        tsum += v[q * 4] + v[q * 4 + 1] + v[q * 4 + 2] + v[q * 4 + 3];
    }
    __shared__ int sh[256];
    sh[t] = tsum;
    __syncthreads();
    for (int off = 1; off < 256; off <<= 1) {
        int u = (t >= off) ? sh[t - off] : 0;
        __syncthreads();
        sh[t] += u;
        __syncthreads();
    }
    int run = ((t == 0) ? 0 : sh[t - 1]) + boff[blockIdx.x];
#pragma unroll
    for (int q = 0; q < 8; ++q) {
        int b = base + q * 4;
        int o0 = run;            run += v[q * 4 + 0];
        int o1 = run;            run += v[q * 4 + 1];
        int o2 = run;            run += v[q * 4 + 2];
        int o3 = run;            run += v[q * 4 + 3];
        if (b + 3 < M) { *(int4*)(a + b) = make_int4(o0, o1, o2, o3); }
        else {
            if (b     < M) a[b]     = o0;
            if (b + 1 < M) a[b + 1] = o1;
            if (b + 2 < M) a[b + 2] = o2;
            if (b + 3 < M) a[b + 3] = o3;
        }
    }
    if (blockIdx.x == 0 && t == 0) a[M] = E;
}

// ---------- p1 scatter: edges -> group-contiguous part[], LDS cursors ----------
__global__ __launch_bounds__(256) void k_p1scat(const int* __restrict__ src,
                                                const int* __restrict__ dst,
                                                const int* __restrict__ S,
                                                unsigned int* __restrict__ part,
                                                int E, int G, int NB1) {
    __shared__ int lcur[512];
    int t = threadIdx.x;
    for (int g = t; g < G; g += 256) lcur[g] = S[(size_t)g * NB1 + blockIdx.x];
    __syncthreads();
    int lo = blockIdx.x * CHUNK1;
    int hi = min(E, lo + CHUNK1);
    for (int e = lo + t; e < hi; e += 256) {
        int d = __builtin_nontemporal_load(dst + e);
        int s = __builtin_nontemporal_load(src + e);
        int pos = atomicAdd(&lcur[d >> GBITS], 1);
        part[pos] = ((unsigned)s << GBITS) | (unsigned)(d & ((1 << GBITS) - 1));
    }
}

// ---------- p2: per-group fine CSR in LDS -> rowptr/dinv/esorted ----------
__global__ __launch_bounds__(256) void k_p2(const unsigned int* __restrict__ part,
                                            const int* __restrict__ S,
                                            int* __restrict__ rowptr,
                                            float* __restrict__ dinv,
                                            int* __restrict__ esorted,
                                            int E, int N, int G, int NB1) {
    __shared__ int lcnt[256], lpre[256], lcur[256];
    int t = threadIdx.x;
    int g = blockIdx.x;
    int base = S[(size_t)g * NB1];
    int end  = (g == G - 1) ? E : S[(size_t)(g + 1) * NB1];
    lcnt[t] = 0;
    __syncthreads();
    for (int i = base + t; i < end; i += 256) {
        unsigned p = part[i];
        atomicAdd(&lcnt[p & 255], 1);
    }
    __syncthreads();
    int v = lcnt[t];
    lpre[t] = v;
    __syncthreads();
    for (int off = 1; off < 256; off <<= 1) {
        int u = (t >= off) ? lpre[t - off] : 0;
        __syncthreads();
        lpre[t] += u;
        __syncthreads();
    }
    int excl = (t == 0) ? 0 : lpre[t - 1];
    lcur[t] = base + excl;                       // global cursor
    int node = (g << GBITS) + t;
    if (node < N) {
        rowptr[node] = base + excl;
        dinv[node] = rsqrtf(1.0f + (float)v);
    }
    if (g == 0 && t == 0) rowptr[N] = E;
    __syncthreads();
    for (int i = base + t; i < end; i += 256) {
        unsigned p = part[i];
        int pos = atomicAdd(&lcur[p & 255], 1);
        esorted[pos] = (int)(p >> GBITS);
    }
}

// ---------------- layer 1 GEMM: hp1h = fp16( dinv * (x @ W1) ) ----------------
__global__ __launch_bounds__(256) void k_gemm1(const float* __restrict__ x,
                                               const float* __restrict__ W1,
                                               const float* __restrict__ dinv,
                                               __half* __restrict__ hp1h, int N) {
    __shared__ float sW[IN_CH * HID];
    __shared__ float sx[16 * IN_CH];
    const int tid = threadIdx.x;
    const int node0 = blockIdx.x * 16;

    {
        const float4* g = (const float4*)W1;
        float4* s = (float4*)sW;
        for (int i = tid; i < IN_CH * HID / 4; i += 256) s[i] = g[i];
    }
    {
        const float4* g = (const float4*)(x + (size_t)node0 * IN_CH);
        float4* s = (float4*)sx;
        for (int i = tid; i < 16 * IN_CH / 4; i += 256) s[i] = g[i];
    }
    __syncthreads();

    const int k  = tid & 63;
    const int n0 = tid >> 6;  // 0..3
    float a0 = 0.f, a1 = 0.f, a2 = 0.f, a3 = 0.f;
#pragma unroll 8
    for (int j = 0; j < IN_CH; ++j) {
        float w = sW[j * HID + k];
        a0 = fmaf(sx[(n0     ) * IN_CH + j], w, a0);
        a1 = fmaf(sx[(n0 +  4) * IN_CH + j], w, a1);
        a2 = fmaf(sx[(n0 +  8) * IN_CH + j], w, a2);
        a3 = fmaf(sx[(n0 + 12) * IN_CH + j], w, a3);
    }
    hp1h[(size_t)(node0 + n0     ) * HID + k] = __float2half(a0 * dinv[node0 + n0]);
    hp1h[(size_t)(node0 + n0 +  4) * HID + k] = __float2half(a1 * dinv[node0 + n0 + 4]);
    hp1h[(size_t)(node0 + n0 +  8) * HID + k] = __float2half(a2 * dinv[node0 + n0 + 8]);
    hp1h[(size_t)(node0 + n0 + 12) * HID + k] = __float2half(a3 * dinv[node0 + n0 + 12]);
}

// ---- layer 1 aggregate + relu + bias + layer 2 projection, fused ----
// One wave per node; TWO edges per wave step: lanes 0-31 edge e, lanes 32-63
// edge e+1, each lane owns 2 dims via one half2 load (one 256B wave-load
// covers two fp16 rows). 4 pair-accumulators keep 4 gathers in flight.
__global__ __launch_bounds__(256) void k_agg1(const int* __restrict__ rowptr,
                                              const int* __restrict__ esorted,
                                              const __half2* __restrict__ hp1h,
                                              const float* __restrict__ dinv,
                                              const float* __restrict__ b1,
                                              const float* __restrict__ W2,
                                              float* __restrict__ hp2, int N) {
    int wid = (blockIdx.x * blockDim.x + threadIdx.x) >> 6;
    if (wid >= N) return;
    const int lane = threadIdx.x & 63;
    const int k32  = lane & 31;
    const int half = lane >> 5;
    int beg = rowptr[wid], end = rowptr[wid + 1];

    float a0x = 0.f, a0y = 0.f, a1x = 0.f, a1y = 0.f;
    float a2x = 0.f, a2y = 0.f, a3x = 0.f, a3y = 0.f;
    int e = beg;
    for (; e + 7 < end; e += 8) {
        int sa0 = esorted[e + 0], sb0 = esorted[e + 1];   // wave-uniform loads
        int sa1 = esorted[e + 2], sb1 = esorted[e + 3];
        int sa2 = esorted[e + 4], sb2 = esorted[e + 5];
        int sa3 = esorted[e + 6], sb3 = esorted[e + 7];
        int s0 = half ? sb0 : sa0;
        int s1 = half ? sb1 : sa1;
        int s2 = half ? sb2 : sa2;
        int s3 = half ? sb3 : sa3;
        float2 f0 = __half22float2(hp1h[(size_t)s0 * 32 + k32]);
        float2 f1 = __half22float2(hp1h[(size_t)s1 * 32 + k32]);
        float2 f2 = __half22float2(hp1h[(size_t)s2 * 32 + k32]);
        float2 f3 = __half22float2(hp1h[(size_t)s3 * 32 + k32]);
        a0x += f0.x; a0y += f0.y;
        a1x += f1.x; a1y += f1.y;
        a2x += f2.x; a2y += f2.y;
        a3x += f3.x; a3y += f3.y;
    }
    for (; e < end; e += 2) {
        int idx = e + half;
        int s = esorted[(idx < end) ? idx : e];
        float2 f = __half22float2(hp1h[(size_t)s * 32 + k32]);
        float w = (idx < end) ? 1.f : 0.f;
        a0x = fmaf(f.x, w, a0x);
        a0y = fmaf(f.y, w, a0y);
    }
    float ax = (a0x + a1x) + (a2x + a3x);
    float ay = (a0y + a1y) + (a2y + a3y);
    ax += __shfl_xor(ax, 32);   // combine the two half-wave edge sets
    ay += __shfl_xor(ay, 32);

    float2 fs = __half22float2(hp1h[(size_t)wid * 32 + k32]);  // self-loop
    ax += fs.x;
    ay += fs.y;

    float dj = dinv[wid];
    float2 bb = *(const float2*)(b1 + 2 * k32);
    float h0 = fmaxf(fmaf(dj, ax, bb.x), 0.0f);
    float h1 = fmaxf(fmaf(dj, ay, bb.y), 0.0f);
    float4 w4 = *(const float4*)(W2 + 4 * k32);  // W2[2k][0..1], W2[2k+1][0..1]
    float p0 = h0 * w4.x + h1 * w4.z;
    float p1 = h0 * w4.y + h1 * w4.w;
#pragma unroll
    for (int off = 32; off; off >>= 1) {
        p0 += __shfl_xor(p0, off);
        p1 += __shfl_xor(p1, off);
    }
    if (lane == 0) {   // halves are duplicates after the xor-32 combine -> x0.5
        hp2[(size_t)wid * 2 + 0] = p0 * 0.5f * dj;
        hp2[(size_t)wid * 2 + 1] = p1 * 0.5f * dj;
    }
}

// ---------------- layer 2 aggregate + epilogue ----------------
__global__ __launch_bounds__(256) void k_agg2(const int* __restrict__ rowptr,
                                              const int* __restrict__ esorted,
                                              const float* __restrict__ hp2,
                                              const float* __restrict__ dinv,
                                              const float* __restrict__ b2,
                                              float* __restrict__ out, int N) {
    int gid = blockIdx.x * blockDim.x + threadIdx.x;
    int j = gid >> 3;
    if (j >= N) return;
    int l = gid & 7;
    int beg = rowptr[j], end = rowptr[j + 1];
    float ax = 0.f, ay = 0.f;
    for (int e = beg + l; e < end; e += 8) {
        int s = esorted[e];
        float2 v = *(const float2*)(hp2 + (size_t)s * 2);
        ax += v.x;
        ay += v.y;
    }
#pragma unroll
    for (int off = 1; off < 8; off <<= 1) {
        ax += __shfl_xor(ax, off);
        ay += __shfl_xor(ay, off);
    }
    if (l == 0) {
        float2 self = *(const float2*)(hp2 + (size_t)j * 2);
        float dj = dinv[j];
        out[(size_t)j * 2 + 0] = fmaf(dj, ax + self.x, b2[0]);
        out[(size_t)j * 2 + 1] = fmaf(dj, ay + self.y, b2[1]);
    }
}

extern "C" void kernel_launch(void* const* d_in, const int* in_sizes, int n_in,
                              void* d_out, int out_size, void* d_ws, size_t ws_size,
                              hipStream_t stream) {
    const float* x  = (const float*)d_in[0];
    const int*   ei = (const int*)d_in[1];
    const float* W1 = (const float*)d_in[2];
    const float* b1 = (const float*)d_in[3];
    const float* W2 = (const float*)d_in[4];
    const float* b2 = (const float*)d_in[5];
    float* out = (float*)d_out;

    const int N = in_sizes[0] / IN_CH;   // 100000
    const int E = in_sizes[1] / 2;       // 3200000
    const int* src = ei;
    const int* dst = ei + E;

    const int G   = (N + 255) >> GBITS;             // 391 groups of 256 nodes
    const int NB1 = (E + CHUNK1 - 1) / CHUNK1;      // 196 p1 blocks
    const int M   = G * NB1;                        // 76636 counts
    const int NBs = (M + SCAN_CHUNK - 1) / SCAN_CHUNK;  // 10 (<=128 required)

    char* ws = (char*)d_ws;
    size_t o = 0;
    auto carve = [&](size_t bytes) -> char* {
        char* p = ws + o;
        o = (o + bytes + 255) & ~(size_t)255;
        return p;
    };
    int*          S       = (int*)carve(((size_t)M + 1) * 4);       // counts -> scanned
    unsigned int* part    = (unsigned int*)carve((size_t)E * 4);    // 12.8 MB
    int*          rowptr  = (int*)carve(((size_t)N + 1) * 4);
    float*        dinv    = (float*)carve((size_t)N * 4);
    int*          bsum    = (int*)carve(128 * 4);
    int*          esorted = (int*)carve((size_t)E * 4);             // 12.8 MB
    __half*       hp1h    = (__half*)carve((size_t)N * HID * 2);    // 12.8 MB fp16
    float*        hp2     = (float*)carve((size_t)N * 2 * 4);
    (void)ws_size;

    k_p1count<<<NB1, 256, 0, stream>>>(dst, S, E, G, NB1);
    k_scan_blocksum<<<NBs, 256, 0, stream>>>(S, bsum, M);
    k_scan_bsums<<<1, 128, 0, stream>>>(bsum, NBs);
    k_scan_apply<<<NBs, 256, 0, stream>>>(S, bsum, M, E);
    k_p1scat<<<NB1, 256, 0, stream>>>(src, dst, S, part, E, G, NB1);
    k_p2<<<G, 256, 0, stream>>>(part, S, rowptr, dinv, esorted, E, N, G, NB1);

    k_gemm1<<<(N + 15) / 16, 256, 0, stream>>>(x, W1, dinv, hp1h, N);
    k_agg1<<<(unsigned)(((size_t)N * 64 + 255) / 256), 256, 0, stream>>>(
        rowptr, esorted, (const __half2*)hp1h, dinv, b1, W2, hp2, N);
    k_agg2<<<(unsigned)(((size_t)N * 8 + 255) / 256), 256, 0, stream>>>(
        rowptr, esorted, hp2, dinv, b2, out, N);
}

// Round 10
// 233.078 us; speedup vs baseline: 2.4944x; 1.0888x over previous
//
#include <hip/hip_runtime.h>
#include <hip/hip_fp16.h>

#define IN_CH 128
#define HID 64
#define CHUNK1 16384   // edges per p1 block
#define GBITS 8        // 256 nodes per group
#define SCAN_CHUNK 8192

// ---------- p1 count: LDS histogram of dst>>8 per edge-chunk ----------
__global__ __launch_bounds__(512) void k_p1count(const int* __restrict__ dst,
                                                 int* __restrict__ C,
                                                 int E, int G, int NB1) {
    __shared__ int lcnt[512];
    int t = threadIdx.x;
    for (int i = t; i < G; i += 512) lcnt[i] = 0;
    __syncthreads();
    int lo = blockIdx.x * CHUNK1;
    int hi = min(E, lo + CHUNK1);
    for (int e = lo + t; e < hi; e += 512) {
        int d = __builtin_nontemporal_load(dst + e);
        atomicAdd(&lcnt[d >> GBITS], 1);
    }
    __syncthreads();
    for (int g = t; g < G; g += 512) C[(size_t)g * NB1 + blockIdx.x] = lcnt[g];
}

// ---------- multi-block exclusive scan, in place (R5-verified) ----------
__global__ __launch_bounds__(256) void k_scan_blocksum(const int* __restrict__ a,
                                                       int* __restrict__ bsum, int M) {
    int t = threadIdx.x;
    int base = blockIdx.x * SCAN_CHUNK + t * 32;
    int s = 0;
#pragma unroll
    for (int q = 0; q < 8; ++q) {
        int b = base + q * 4;
        if (b + 3 < M) {
            int4 v = *(const int4*)(a + b);
            s += v.x + v.y + v.z + v.w;
        } else {
            for (int i = 0; i < 4; ++i) if (b + i < M) s += a[b + i];
        }
    }
#pragma unroll
    for (int off = 32; off; off >>= 1) s += __shfl_down(s, off);
    __shared__ int ws[4];
    if ((t & 63) == 0) ws[t >> 6] = s;
    __syncthreads();
    if (t == 0) bsum[blockIdx.x] = ws[0] + ws[1] + ws[2] + ws[3];
}

__global__ __launch_bounds__(128) void k_scan_bsums(int* __restrict__ bsum, int nb) {
    __shared__ int sh[128];
    int t = threadIdx.x;
    int v = (t < nb) ? bsum[t] : 0;
    sh[t] = v;
    __syncthreads();
    for (int off = 1; off < 128; off <<= 1) {
        int u = (t >= off) ? sh[t - off] : 0;
        __syncthreads();
        sh[t] += u;
        __syncthreads();
    }
    if (t < nb) bsum[t] = (t == 0) ? 0 : sh[t - 1];
}

__global__ __launch_bounds__(256) void k_scan_apply(int* __restrict__ a,
                                                    const int* __restrict__ boff,
                                                    int M, int E) {
    int t = threadIdx.x;
    int base = blockIdx.x * SCAN_CHUNK + t * 32;
    int v[32];
    int tsum = 0;
#pragma unroll
    for (int q = 0; q < 8; ++q) {
        int b = base + q * 4;
        if (b + 3 < M) {
            int4 w = *(const int4*)(a + b);
            v[q * 4 + 0] = w.x; v[q * 4 + 1] = w.y; v[q * 4 + 2] = w.z; v[q * 4 + 3] = w.w;
        } else {
            for (int i = 0; i < 4; ++i) v[q * 4 + i] = (b + i < M) ? a[b + i] : 0;
        }
        tsum += v[q * 4] + v[q * 4 + 1] + v[q * 4 + 2] + v[q * 4 + 3];
    }
    __shared__ int sh[256];
    sh[t] = tsum;
    __syncthreads();
    for (int off = 1; off < 256; off <<= 1) {
        int u = (t >= off) ? sh[t - off] : 0;
        __syncthreads();
        sh[t] += u;
        __syncthreads();
    }
    int run = ((t == 0) ? 0 : sh[t - 1]) + boff[blockIdx.x];
#pragma unroll
    for (int q = 0; q < 8; ++q) {
        int b = base + q * 4;
        int o0 = run;            run += v[q * 4 + 0];
        int o1 = run;            run += v[q * 4 + 1];
        int o2 = run;            run += v[q * 4 + 2];
        int o3 = run;            run += v[q * 4 + 3];
        if (b + 3 < M) { *(int4*)(a + b) = make_int4(o0, o1, o2, o3); }
        else {
            if (b     < M) a[b]     = o0;
            if (b + 1 < M) a[b + 1] = o1;
            if (b + 2 < M) a[b + 2] = o2;
            if (b + 3 < M) a[b + 3] = o3;
        }
    }
    if (blockIdx.x == 0 && t == 0) a[M] = E;
}

// ---------- p1 scatter: edges -> group-contiguous part[], LDS cursors ----------
__global__ __launch_bounds__(512) void k_p1scat(const int* __restrict__ src,
                                                const int* __restrict__ dst,
                                                const int* __restrict__ S,
                                                unsigned int* __restrict__ part,
                                                int E, int G, int NB1) {
    __shared__ int lcur[512];
    int t = threadIdx.x;
    for (int g = t; g < G; g += 512) lcur[g] = S[(size_t)g * NB1 + blockIdx.x];
    __syncthreads();
    int lo = blockIdx.x * CHUNK1;
    int hi = min(E, lo + CHUNK1);
    for (int e = lo + t; e < hi; e += 512) {
        int d = __builtin_nontemporal_load(dst + e);
        int s = __builtin_nontemporal_load(src + e);
        int pos = atomicAdd(&lcur[d >> GBITS], 1);
        part[pos] = ((unsigned)s << GBITS) | (unsigned)(d & ((1 << GBITS) - 1));
    }
}

// ---------- p2: per-group fine CSR in LDS -> rowptr/dinv/esorted ----------
__global__ __launch_bounds__(512) void k_p2(const unsigned int* __restrict__ part,
                                            const int* __restrict__ S,
                                            int* __restrict__ rowptr,
                                            float* __restrict__ dinv,
                                            int* __restrict__ esorted,
                                            int E, int N, int G, int NB1) {
    __shared__ int lcnt[256], lpre[256], lcur[256];
    int t = threadIdx.x;
    int g = blockIdx.x;
    int base = S[(size_t)g * NB1];
    int end  = (g == G - 1) ? E : S[(size_t)(g + 1) * NB1];
    if (t < 256) lcnt[t] = 0;
    __syncthreads();
    for (int i = base + t; i < end; i += 512) {
        unsigned p = part[i];
        atomicAdd(&lcnt[p & 255], 1);
    }
    __syncthreads();
    int v = 0;
    if (t < 256) {
        v = lcnt[t];
        lpre[t] = v;
    }
    __syncthreads();
    for (int off = 1; off < 256; off <<= 1) {
        int u = (t >= off && t < 256) ? lpre[t - off] : 0;
        __syncthreads();
        if (t < 256) lpre[t] += u;
        __syncthreads();
    }
    if (t < 256) {
        int excl = (t == 0) ? 0 : lpre[t - 1];
        lcur[t] = base + excl;                   // global cursor
        int node = (g << GBITS) + t;
        if (node < N) {
            rowptr[node] = base + excl;
            dinv[node] = rsqrtf(1.0f + (float)v);
        }
    }
    if (g == 0 && t == 0) rowptr[N] = E;
    __syncthreads();
    for (int i = base + t; i < end; i += 512) {
        unsigned p = part[i];
        int pos = atomicAdd(&lcur[p & 255], 1);
        esorted[pos] = (int)(p >> GBITS);
    }
}

// ---------------- layer 1 GEMM: hp1h = fp16( dinv * (x @ W1) ) ----------------
__global__ __launch_bounds__(256) void k_gemm1(const float* __restrict__ x,
                                               const float* __restrict__ W1,
                                               const float* __restrict__ dinv,
                                               __half* __restrict__ hp1h, int N) {
    __shared__ float sW[IN_CH * HID];
    __shared__ float sx[16 * IN_CH];
    const int tid = threadIdx.x;
    const int node0 = blockIdx.x * 16;

    {
        const float4* g = (const float4*)W1;
        float4* s = (float4*)sW;
        for (int i = tid; i < IN_CH * HID / 4; i += 256) s[i] = g[i];
    }
    {
        const float4* g = (const float4*)(x + (size_t)node0 * IN_CH);
        float4* s = (float4*)sx;
        for (int i = tid; i < 16 * IN_CH / 4; i += 256) s[i] = g[i];
    }
    __syncthreads();

    const int k  = tid & 63;
    const int n0 = tid >> 6;  // 0..3
    float a0 = 0.f, a1 = 0.f, a2 = 0.f, a3 = 0.f;
#pragma unroll 8
    for (int j = 0; j < IN_CH; ++j) {
        float w = sW[j * HID + k];
        a0 = fmaf(sx[(n0     ) * IN_CH + j], w, a0);
        a1 = fmaf(sx[(n0 +  4) * IN_CH + j], w, a1);
        a2 = fmaf(sx[(n0 +  8) * IN_CH + j], w, a2);
        a3 = fmaf(sx[(n0 + 12) * IN_CH + j], w, a3);
    }
    hp1h[(size_t)(node0 + n0     ) * HID + k] = __float2half(a0 * dinv[node0 + n0]);
    hp1h[(size_t)(node0 + n0 +  4) * HID + k] = __float2half(a1 * dinv[node0 + n0 + 4]);
    hp1h[(size_t)(node0 + n0 +  8) * HID + k] = __float2half(a2 * dinv[node0 + n0 + 8]);
    hp1h[(size_t)(node0 + n0 + 12) * HID + k] = __float2half(a3 * dinv[node0 + n0 + 12]);
}

// ---- layer 1 aggregate + relu + bias + layer 2 projection, fused ----
// One wave per node. Fast path: 16 edges/iter; each half-wave loads its own
// 8 indices (no select chain), gathers 8 rows, reduces them with packed
// v_pk_add_f16 in a pairwise tree (partials of <=4 terms, |v|~0.35 -> fp16
// rounding ~2e-4 pre-dinv, negligible), flushes to f32 masters. 8 gathers
// in flight; ~2.4 wave-ops/edge vs 4.5 before.
__global__ __launch_bounds__(256) void k_agg1(const int* __restrict__ rowptr,
                                              const int* __restrict__ esorted,
                                              const __half2* __restrict__ hp1h,
                                              const float* __restrict__ dinv,
                                              const float* __restrict__ b1,
                                              const float* __restrict__ W2,
                                              float* __restrict__ hp2, int N) {
    int wid = (blockIdx.x * blockDim.x + threadIdx.x) >> 6;
    if (wid >= N) return;
    const int lane = threadIdx.x & 63;
    const int k32  = lane & 31;
    const int half = lane >> 5;
    int beg = rowptr[wid], end = rowptr[wid + 1];

    float ax = 0.f, ay = 0.f;
    int e = beg;
    for (; e + 15 < end; e += 16) {
        const int* ep = esorted + e + 8 * half;   // this half-wave's 8 edges
        int s0 = ep[0], s1 = ep[1], s2 = ep[2], s3 = ep[3];
        int s4 = ep[4], s5 = ep[5], s6 = ep[6], s7 = ep[7];
        __half2 h0 = hp1h[(unsigned)(s0 * 32 + k32)];
        __half2 h1 = hp1h[(unsigned)(s1 * 32 + k32)];
        __half2 h2 = hp1h[(unsigned)(s2 * 32 + k32)];
        __half2 h3 = hp1h[(unsigned)(s3 * 32 + k32)];
        h0 = __hadd2(h0, hp1h[(unsigned)(s4 * 32 + k32)]);
        h1 = __hadd2(h1, hp1h[(unsigned)(s5 * 32 + k32)]);
        h2 = __hadd2(h2, hp1h[(unsigned)(s6 * 32 + k32)]);
        h3 = __hadd2(h3, hp1h[(unsigned)(s7 * 32 + k32)]);
        float2 f0 = __half22float2(__hadd2(h0, h1));
        float2 f1 = __half22float2(__hadd2(h2, h3));
        ax += f0.x + f1.x;
        ay += f0.y + f1.y;
    }
    for (; e + 1 < end; e += 2) {                 // pairs: half-wave h takes e+h
        int s = esorted[e + half];
        float2 f = __half22float2(hp1h[(unsigned)(s * 32 + k32)]);
        ax += f.x;
        ay += f.y;
    }
    if (e < end) {                                // odd final edge: half 0 only
        int s = esorted[e];
        float2 f = __half22float2(hp1h[(unsigned)(s * 32 + k32)]);
        if (half == 0) { ax += f.x; ay += f.y; }
    }
    ax += __shfl_xor(ax, 32);                     // combine half-wave edge sets
    ay += __shfl_xor(ay, 32);

    float2 fs = __half22float2(hp1h[(unsigned)(wid * 32 + k32)]);  // self-loop
    ax += fs.x;
    ay += fs.y;

    float dj = dinv[wid];
    float2 bb = *(const float2*)(b1 + 2 * k32);
    float h0 = fmaxf(fmaf(dj, ax, bb.x), 0.0f);
    float h1 = fmaxf(fmaf(dj, ay, bb.y), 0.0f);
    float4 w4 = *(const float4*)(W2 + 4 * k32);
    float p0 = h0 * w4.x + h1 * w4.z;
    float p1 = h0 * w4.y + h1 * w4.w;
#pragma unroll
    for (int off = 32; off; off >>= 1) {
        p0 += __shfl_xor(p0, off);
        p1 += __shfl_xor(p1, off);
    }
    if (lane == 0) {   // halves are duplicates after the xor-32 combine -> x0.5
        hp2[(size_t)wid * 2 + 0] = p0 * 0.5f * dj;
        hp2[(size_t)wid * 2 + 1] = p1 * 0.5f * dj;
    }
}

// ---------------- layer 2 aggregate + epilogue ----------------
__global__ __launch_bounds__(256) void k_agg2(const int* __restrict__ rowptr,
                                              const int* __restrict__ esorted,
                                              const float* __restrict__ hp2,
                                              const float* __restrict__ dinv,
                                              const float* __restrict__ b2,
                                              float* __restrict__ out, int N) {
    int gid = blockIdx.x * blockDim.x + threadIdx.x;
    int j = gid >> 3;
    if (j >= N) return;
    int l = gid & 7;
    int beg = rowptr[j], end = rowptr[j + 1];
    float ax = 0.f, ay = 0.f;
    for (int e = beg + l; e < end; e += 8) {
        int s = esorted[e];
        float2 v = *(const float2*)(hp2 + (size_t)s * 2);
        ax += v.x;
        ay += v.y;
    }
#pragma unroll
    for (int off = 1; off < 8; off <<= 1) {
        ax += __shfl_xor(ax, off);
        ay += __shfl_xor(ay, off);
    }
    if (l == 0) {
        float2 self = *(const float2*)(hp2 + (size_t)j * 2);
        float dj = dinv[j];
        out[(size_t)j * 2 + 0] = fmaf(dj, ax + self.x, b2[0]);
        out[(size_t)j * 2 + 1] = fmaf(dj, ay + self.y, b2[1]);
    }
}

extern "C" void kernel_launch(void* const* d_in, const int* in_sizes, int n_in,
                              void* d_out, int out_size, void* d_ws, size_t ws_size,
                              hipStream_t stream) {
    const float* x  = (const float*)d_in[0];
    const int*   ei = (const int*)d_in[1];
    const float* W1 = (const float*)d_in[2];
    const float* b1 = (const float*)d_in[3];
    const float* W2 = (const float*)d_in[4];
    const float* b2 = (const float*)d_in[5];
    float* out = (float*)d_out;

    const int N = in_sizes[0] / IN_CH;   // 100000
    const int E = in_sizes[1] / 2;       // 3200000
    const int* src = ei;
    const int* dst = ei + E;

    const int G   = (N + 255) >> GBITS;             // 391 groups of 256 nodes
    const int NB1 = (E + CHUNK1 - 1) / CHUNK1;      // 196 p1 blocks
    const int M   = G * NB1;                        // 76636 counts
    const int NBs = (M + SCAN_CHUNK - 1) / SCAN_CHUNK;  // 10 (<=128 required)

    char* ws = (char*)d_ws;
    size_t o = 0;
    auto carve = [&](size_t bytes) -> char* {
        char* p = ws + o;
        o = (o + bytes + 255) & ~(size_t)255;
        return p;
    };
    int*          S       = (int*)carve(((size_t)M + 1) * 4);       // counts -> scanned
    unsigned int* part    = (unsigned int*)carve((size_t)E * 4);    // 12.8 MB
    int*          rowptr  = (int*)carve(((size_t)N + 1) * 4);
    float*        dinv    = (float*)carve((size_t)N * 4);
    int*          bsum    = (int*)carve(128 * 4);
    int*          esorted = (int*)carve((size_t)E * 4);             // 12.8 MB
    __half*       hp1h    = (__half*)carve((size_t)N * HID * 2);    // 12.8 MB fp16
    float*        hp2     = (float*)carve((size_t)N * 2 * 4);
    (void)ws_size;

    k_p1count<<<NB1, 512, 0, stream>>>(dst, S, E, G, NB1);
    k_scan_blocksum<<<NBs, 256, 0, stream>>>(S, bsum, M);
    k_scan_bsums<<<1, 128, 0, stream>>>(bsum, NBs);
    k_scan_apply<<<NBs, 256, 0, stream>>>(S, bsum, M, E);
    k_p1scat<<<NB1, 512, 0, stream>>>(src, dst, S, part, E, G, NB1);
    k_p2<<<G, 512, 0, stream>>>(part, S, rowptr, dinv, esorted, E, N, G, NB1);

    k_gemm1<<<(N + 15) / 16, 256, 0, stream>>>(x, W1, dinv, hp1h, N);
    k_agg1<<<(unsigned)(((size_t)N * 64 + 255) / 256), 256, 0, stream>>>(
        rowptr, esorted, (const __half2*)hp1h, dinv, b1, W2, hp2, N);
    k_agg2<<<(unsigned)(((size_t)N * 8 + 255) / 256), 256, 0, stream>>>(
        rowptr, esorted, hp2, dinv, b2, out, N);
}

// Round 11
// 231.304 us; speedup vs baseline: 2.5136x; 1.0077x over previous
//
#include <hip/hip_runtime.h>
#include <hip/hip_fp16.h>

#define IN_CH 128
#define HID 64
#define CHUNK1 16384   // edges per p1 block
#define GBITS 8        // 256 nodes per group
#define SCAN_CHUNK 8192

// ---------- p1 count: LDS histogram of dst>>8 per edge-chunk ----------
__global__ __launch_bounds__(512) void k_p1count(const int* __restrict__ dst,
                                                 int* __restrict__ C,
                                                 int E, int G, int NB1) {
    __shared__ int lcnt[512];
    int t = threadIdx.x;
    for (int i = t; i < G; i += 512) lcnt[i] = 0;
    __syncthreads();
    int lo = blockIdx.x * CHUNK1;
    int hi = min(E, lo + CHUNK1);
    for (int e = lo + t; e < hi; e += 512) {
        int d = __builtin_nontemporal_load(dst + e);
        atomicAdd(&lcnt[d >> GBITS], 1);
    }
    __syncthreads();
    for (int g = t; g < G; g += 512) C[(size_t)g * NB1 + blockIdx.x] = lcnt[g];
}

// ---------- multi-block exclusive scan, in place (R5-verified) ----------
__global__ __launch_bounds__(256) void k_scan_blocksum(const int* __restrict__ a,
                                                       int* __restrict__ bsum, int M) {
    int t = threadIdx.x;
    int base = blockIdx.x * SCAN_CHUNK + t * 32;
    int s = 0;
#pragma unroll
    for (int q = 0; q < 8; ++q) {
        int b = base + q * 4;
        if (b + 3 < M) {
            int4 v = *(const int4*)(a + b);
            s += v.x + v.y + v.z + v.w;
        } else {
            for (int i = 0; i < 4; ++i) if (b + i < M) s += a[b + i];
        }
    }
#pragma unroll
    for (int off = 32; off; off >>= 1) s += __shfl_down(s, off);
    __shared__ int ws[4];
    if ((t & 63) == 0) ws[t >> 6] = s;
    __syncthreads();
    if (t == 0) bsum[blockIdx.x] = ws[0] + ws[1] + ws[2] + ws[3];
}

__global__ __launch_bounds__(128) void k_scan_bsums(int* __restrict__ bsum, int nb) {
    __shared__ int sh[128];
    int t = threadIdx.x;
    int v = (t < nb) ? bsum[t] : 0;
    sh[t] = v;
    __syncthreads();
    for (int off = 1; off < 128; off <<= 1) {
        int u = (t >= off) ? sh[t - off] : 0;
        __syncthreads();
        sh[t] += u;
        __syncthreads();
    }
    if (t < nb) bsum[t] = (t == 0) ? 0 : sh[t - 1];
}

__global__ __launch_bounds__(256) void k_scan_apply(int* __restrict__ a,
                                                    const int* __restrict__ boff,
                                                    int M, int E) {
    int t = threadIdx.x;
    int base = blockIdx.x * SCAN_CHUNK + t * 32;
    int v[32];
    int tsum = 0;
#pragma unroll
    for (int q = 0; q < 8; ++q) {
        int b = base + q * 4;
        if (b + 3 < M) {
            int4 w = *(const int4*)(a + b);
            v[q * 4 + 0] = w.x; v[q * 4 + 1] = w.y; v[q * 4 + 2] = w.z; v[q * 4 + 3] = w.w;
        } else {
            for (int i = 0; i < 4; ++i) v[q * 4 + i] = (b + i < M) ? a[b + i] : 0;
        }
        tsum += v[q * 4] + v[q * 4 + 1] + v[q * 4 + 2] + v[q * 4 + 3];
    }
    __shared__ int sh[256];
    sh[t] = tsum;
    __syncthreads();
    for (int off = 1; off < 256; off <<= 1) {
        int u = (t >= off) ? sh[t - off] : 0;
        __syncthreads();
        sh[t] += u;
        __syncthreads();
    }
    int run = ((t == 0) ? 0 : sh[t - 1]) + boff[blockIdx.x];
#pragma unroll
    for (int q = 0; q < 8; ++q) {
        int b = base + q * 4;
        int o0 = run;            run += v[q * 4 + 0];
        int o1 = run;            run += v[q * 4 + 1];
        int o2 = run;            run += v[q * 4 + 2];
        int o3 = run;            run += v[q * 4 + 3];
        if (b + 3 < M) { *(int4*)(a + b) = make_int4(o0, o1, o2, o3); }
        else {
            if (b     < M) a[b]     = o0;
            if (b + 1 < M) a[b + 1] = o1;
            if (b + 2 < M) a[b + 2] = o2;
            if (b + 3 < M) a[b + 3] = o3;
        }
    }
    if (blockIdx.x == 0 && t == 0) a[M] = E;
}

// ---------- p1 scatter: edges -> group-contiguous part[], LDS cursors ----------
__global__ __launch_bounds__(512) void k_p1scat(const int* __restrict__ src,
                                                const int* __restrict__ dst,
                                                const int* __restrict__ S,
                                                unsigned int* __restrict__ part,
                                                int E, int G, int NB1) {
    __shared__ int lcur[512];
    int t = threadIdx.x;
    for (int g = t; g < G; g += 512) lcur[g] = S[(size_t)g * NB1 + blockIdx.x];
    __syncthreads();
    int lo = blockIdx.x * CHUNK1;
    int hi = min(E, lo + CHUNK1);
    for (int e = lo + t; e < hi; e += 512) {
        int d = __builtin_nontemporal_load(dst + e);
        int s = __builtin_nontemporal_load(src + e);
        int pos = atomicAdd(&lcur[d >> GBITS], 1);
        part[pos] = ((unsigned)s << GBITS) | (unsigned)(d & ((1 << GBITS) - 1));
    }
}

// ---------- p2: single-pass per-group CSR build (register-staged rank trick) ----
// Each thread stages <=18 edges in registers (static unroll -> no scratch),
// rank = LDS atomicAdd return; after the LDS scan, scatter directly to
// base + lexc[dlocal] + rank. One pass over part instead of two.
__global__ __launch_bounds__(512) void k_p2(const unsigned int* __restrict__ part,
                                            const int* __restrict__ S,
                                            int* __restrict__ rowptr,
                                            float* __restrict__ dinv,
                                            int* __restrict__ esorted,
                                            int E, int N, int G, int NB1) {
    __shared__ int lcnt[256], lpre[256], lexc[256];
    int t = threadIdx.x;
    int g = blockIdx.x;
    int base = S[(size_t)g * NB1];
    int end  = (g == G - 1) ? E : S[(size_t)(g + 1) * NB1];
    if (t < 256) lcnt[t] = 0;
    __syncthreads();
    unsigned int  ed[18];
    unsigned char rk[18];
#pragma unroll
    for (int q = 0; q < 18; ++q) {
        int i = base + t + q * 512;
        if (i < end) {
            unsigned p = part[i];
            ed[q] = p;
            rk[q] = (unsigned char)atomicAdd(&lcnt[p & 255], 1);  // deg<256 always
        }
    }
    __syncthreads();
    int v = 0;
    if (t < 256) { v = lcnt[t]; lpre[t] = v; }
    __syncthreads();
    for (int off = 1; off < 256; off <<= 1) {
        int u = (t >= off && t < 256) ? lpre[t - off] : 0;
        __syncthreads();
        if (t < 256) lpre[t] += u;
        __syncthreads();
    }
    if (t < 256) {
        int excl = lpre[t] - v;
        lexc[t] = excl;
        int node = (g << GBITS) + t;
        if (node < N) {
            rowptr[node] = base + excl;
            dinv[node] = rsqrtf(1.0f + (float)v);
        }
    }
    if (g == 0 && t == 0) rowptr[N] = E;
    __syncthreads();
#pragma unroll
    for (int q = 0; q < 18; ++q) {
        int i = base + t + q * 512;
        if (i < end) {
            unsigned p = ed[q];
            esorted[base + lexc[p & 255] + (int)rk[q]] = (int)(p >> GBITS);
        }
    }
}

// ---------------- layer 1 GEMM: hp1h = fp16( dinv * (x @ W1) ) ----------------
__global__ __launch_bounds__(256) void k_gemm1(const float* __restrict__ x,
                                               const float* __restrict__ W1,
                                               const float* __restrict__ dinv,
                                               __half* __restrict__ hp1h, int N) {
    __shared__ float sW[IN_CH * HID];
    __shared__ float sx[16 * IN_CH];
    const int tid = threadIdx.x;
    const int node0 = blockIdx.x * 16;

    {
        const float4* g = (const float4*)W1;
        float4* s = (float4*)sW;
        for (int i = tid; i < IN_CH * HID / 4; i += 256) s[i] = g[i];
    }
    {
        const float4* g = (const float4*)(x + (size_t)node0 * IN_CH);
        float4* s = (float4*)sx;
        for (int i = tid; i < 16 * IN_CH / 4; i += 256) s[i] = g[i];
    }
    __syncthreads();

    const int k  = tid & 63;
    const int n0 = tid >> 6;  // 0..3
    float a0 = 0.f, a1 = 0.f, a2 = 0.f, a3 = 0.f;
#pragma unroll 8
    for (int j = 0; j < IN_CH; ++j) {
        float w = sW[j * HID + k];
        a0 = fmaf(sx[(n0     ) * IN_CH + j], w, a0);
        a1 = fmaf(sx[(n0 +  4) * IN_CH + j], w, a1);
        a2 = fmaf(sx[(n0 +  8) * IN_CH + j], w, a2);
        a3 = fmaf(sx[(n0 + 12) * IN_CH + j], w, a3);
    }
    hp1h[(size_t)(node0 + n0     ) * HID + k] = __float2half(a0 * dinv[node0 + n0]);
    hp1h[(size_t)(node0 + n0 +  4) * HID + k] = __float2half(a1 * dinv[node0 + n0 + 4]);
    hp1h[(size_t)(node0 + n0 +  8) * HID + k] = __float2half(a2 * dinv[node0 + n0 + 8]);
    hp1h[(size_t)(node0 + n0 + 12) * HID + k] = __float2half(a3 * dinv[node0 + n0 + 12]);
}

// ---- layer 1 aggregate + relu + bias + layer 2 projection, fused ----
// One wave per node. Main loop: 32 edges/iter, each half-wave loads 16
// indices then issues 16 independent row-gathers (16-deep MLP — R9's 8-deep
// left the gather chain latency-bound at 81us/37% VALU). Combination stays
// two independent 8-gather fp16 trees with <=4-term fp16 partials (R9
// precision). Tails identical to R9.
__global__ __launch_bounds__(256) void k_agg1(const int* __restrict__ rowptr,
                                              const int* __restrict__ esorted,
                                              const __half2* __restrict__ hp1h,
                                              const float* __restrict__ dinv,
                                              const float* __restrict__ b1,
                                              const float* __restrict__ W2,
                                              float* __restrict__ hp2, int N) {
    int wid = (blockIdx.x * blockDim.x + threadIdx.x) >> 6;
    if (wid >= N) return;
    const int lane = threadIdx.x & 63;
    const int k32  = lane & 31;
    const int half = lane >> 5;
    int beg = rowptr[wid], end = rowptr[wid + 1];

    float ax = 0.f, ay = 0.f;
    int e = beg;
    for (; e + 31 < end; e += 32) {
        const int* ep = esorted + e + 16 * half;   // this half-wave's 16 edges
        int s0 = ep[0],  s1 = ep[1],  s2 = ep[2],  s3 = ep[3];
        int s4 = ep[4],  s5 = ep[5],  s6 = ep[6],  s7 = ep[7];
        int s8 = ep[8],  s9 = ep[9],  sa = ep[10], sb = ep[11];
        int sc = ep[12], sd = ep[13], se = ep[14], sf = ep[15];
        __half2 g0 = hp1h[(unsigned)(s0 * 32 + k32)];
        __half2 g1 = hp1h[(unsigned)(s1 * 32 + k32)];
        __half2 g2 = hp1h[(unsigned)(s2 * 32 + k32)];
        __half2 g3 = hp1h[(unsigned)(s3 * 32 + k32)];
        __half2 g4 = hp1h[(unsigned)(s4 * 32 + k32)];
        __half2 g5 = hp1h[(unsigned)(s5 * 32 + k32)];
        __half2 g6 = hp1h[(unsigned)(s6 * 32 + k32)];
        __half2 g7 = hp1h[(unsigned)(s7 * 32 + k32)];
        __half2 g8 = hp1h[(unsigned)(s8 * 32 + k32)];
        __half2 g9 = hp1h[(unsigned)(s9 * 32 + k32)];
        __half2 ga = hp1h[(unsigned)(sa * 32 + k32)];
        __half2 gb = hp1h[(unsigned)(sb * 32 + k32)];
        __half2 gc = hp1h[(unsigned)(sc * 32 + k32)];
        __half2 gd = hp1h[(unsigned)(sd * 32 + k32)];
        __half2 ge = hp1h[(unsigned)(se * 32 + k32)];
        __half2 gf = hp1h[(unsigned)(sf * 32 + k32)];
        // tree A (g0..g7): partials <=4 fp16 terms, then f32
        __half2 h0 = __hadd2(g0, g4), h1 = __hadd2(g1, g5);
        __half2 h2 = __hadd2(g2, g6), h3 = __hadd2(g3, g7);
        float2 f0 = __half22float2(__hadd2(h0, h1));
        float2 f1 = __half22float2(__hadd2(h2, h3));
        // tree B (g8..gf)
        __half2 h4 = __hadd2(g8, gc), h5 = __hadd2(g9, gd);
        __half2 h6 = __hadd2(ga, ge), h7 = __hadd2(gb, gf);
        float2 f2 = __half22float2(__hadd2(h4, h5));
        float2 f3 = __half22float2(__hadd2(h6, h7));
        ax += (f0.x + f1.x) + (f2.x + f3.x);
        ay += (f0.y + f1.y) + (f2.y + f3.y);
    }
    for (; e + 15 < end; e += 16) {
        const int* ep = esorted + e + 8 * half;    // this half-wave's 8 edges
        int s0 = ep[0], s1 = ep[1], s2 = ep[2], s3 = ep[3];
        int s4 = ep[4], s5 = ep[5], s6 = ep[6], s7 = ep[7];
        __half2 h0 = hp1h[(unsigned)(s0 * 32 + k32)];
        __half2 h1 = hp1h[(unsigned)(s1 * 32 + k32)];
        __half2 h2 = hp1h[(unsigned)(s2 * 32 + k32)];
        __half2 h3 = hp1h[(unsigned)(s3 * 32 + k32)];
        h0 = __hadd2(h0, hp1h[(unsigned)(s4 * 32 + k32)]);
        h1 = __hadd2(h1, hp1h[(unsigned)(s5 * 32 + k32)]);
        h2 = __hadd2(h2, hp1h[(unsigned)(s6 * 32 + k32)]);
        h3 = __hadd2(h3, hp1h[(unsigned)(s7 * 32 + k32)]);
        float2 f0 = __half22float2(__hadd2(h0, h1));
        float2 f1 = __half22float2(__hadd2(h2, h3));
        ax += f0.x + f1.x;
        ay += f0.y + f1.y;
    }
    for (; e + 1 < end; e += 2) {                  // pairs: half-wave h takes e+h
        int s = esorted[e + half];
        float2 f = __half22float2(hp1h[(unsigned)(s * 32 + k32)]);
        ax += f.x;
        ay += f.y;
    }
    if (e < end) {                                 // odd final edge: half 0 only
        int s = esorted[e];
        float2 f = __half22float2(hp1h[(unsigned)(s * 32 + k32)]);
        if (half == 0) { ax += f.x; ay += f.y; }
    }
    ax += __shfl_xor(ax, 32);                      // combine half-wave edge sets
    ay += __shfl_xor(ay, 32);

    float2 fs = __half22float2(hp1h[(unsigned)(wid * 32 + k32)]);  // self-loop
    ax += fs.x;
    ay += fs.y;

    float dj = dinv[wid];
    float2 bb = *(const float2*)(b1 + 2 * k32);
    float h0 = fmaxf(fmaf(dj, ax, bb.x), 0.0f);
    float h1 = fmaxf(fmaf(dj, ay, bb.y), 0.0f);
    float4 w4 = *(const float4*)(W2 + 4 * k32);
    float p0 = h0 * w4.x + h1 * w4.z;
    float p1 = h0 * w4.y + h1 * w4.w;
#pragma unroll
    for (int off = 32; off; off >>= 1) {
        p0 += __shfl_xor(p0, off);
        p1 += __shfl_xor(p1, off);
    }
    if (lane == 0) {   // halves are duplicates after the xor-32 combine -> x0.5
        hp2[(size_t)wid * 2 + 0] = p0 * 0.5f * dj;
        hp2[(size_t)wid * 2 + 1] = p1 * 0.5f * dj;
    }
}

// ---------------- layer 2 aggregate + epilogue ----------------
__global__ __launch_bounds__(256) void k_agg2(const int* __restrict__ rowptr,
                                              const int* __restrict__ esorted,
                                              const float* __restrict__ hp2,
                                              const float* __restrict__ dinv,
                                              const float* __restrict__ b2,
                                              float* __restrict__ out, int N) {
    int gid = blockIdx.x * blockDim.x + threadIdx.x;
    int j = gid >> 3;
    if (j >= N) return;
    int l = gid & 7;
    int beg = rowptr[j], end = rowptr[j + 1];
    float ax = 0.f, ay = 0.f;
    for (int e = beg + l; e < end; e += 8) {
        int s = esorted[e];
        float2 v = *(const float2*)(hp2 + (size_t)s * 2);
        ax += v.x;
        ay += v.y;
    }
#pragma unroll
    for (int off = 1; off < 8; off <<= 1) {
        ax += __shfl_xor(ax, off);
        ay += __shfl_xor(ay, off);
    }
    if (l == 0) {
        float2 self = *(const float2*)(hp2 + (size_t)j * 2);
        float dj = dinv[j];
        out[(size_t)j * 2 + 0] = fmaf(dj, ax + self.x, b2[0]);
        out[(size_t)j * 2 + 1] = fmaf(dj, ay + self.y, b2[1]);
    }
}

extern "C" void kernel_launch(void* const* d_in, const int* in_sizes, int n_in,
                              void* d_out, int out_size, void* d_ws, size_t ws_size,
                              hipStream_t stream) {
    const float* x  = (const float*)d_in[0];
    const int*   ei = (const int*)d_in[1];
    const float* W1 = (const float*)d_in[2];
    const float* b1 = (const float*)d_in[3];
    const float* W2 = (const float*)d_in[4];
    const float* b2 = (const float*)d_in[5];
    float* out = (float*)d_out;

    const int N = in_sizes[0] / IN_CH;   // 100000
    const int E = in_sizes[1] / 2;       // 3200000
    const int* src = ei;
    const int* dst = ei + E;

    const int G   = (N + 255) >> GBITS;             // 391 groups of 256 nodes
    const int NB1 = (E + CHUNK1 - 1) / CHUNK1;      // 196 p1 blocks
    const int M   = G * NB1;                        // 76636 counts
    const int NBs = (M + SCAN_CHUNK - 1) / SCAN_CHUNK;  // 10 (<=128 required)

    char* ws = (char*)d_ws;
    size_t o = 0;
    auto carve = [&](size_t bytes) -> char* {
        char* p = ws + o;
        o = (o + bytes + 255) & ~(size_t)255;
        return p;
    };
    int*          S       = (int*)carve(((size_t)M + 1) * 4);       // counts -> scanned
    unsigned int* part    = (unsigned int*)carve((size_t)E * 4);    // 12.8 MB
    int*          rowptr  = (int*)carve(((size_t)N + 1) * 4);
    float*        dinv    = (float*)carve((size_t)N * 4);
    int*          bsum    = (int*)carve(128 * 4);
    int*          esorted = (int*)carve((size_t)E * 4);             // 12.8 MB
    __half*       hp1h    = (__half*)carve((size_t)N * HID * 2);    // 12.8 MB fp16
    float*        hp2     = (float*)carve((size_t)N * 2 * 4);
    (void)ws_size;

    k_p1count<<<NB1, 512, 0, stream>>>(dst, S, E, G, NB1);
    k_scan_blocksum<<<NBs, 256, 0, stream>>>(S, bsum, M);
    k_scan_bsums<<<1, 128, 0, stream>>>(bsum, NBs);
    k_scan_apply<<<NBs, 256, 0, stream>>>(S, bsum, M, E);
    k_p1scat<<<NB1, 512, 0, stream>>>(src, dst, S, part, E, G, NB1);
    k_p2<<<G, 512, 0, stream>>>(part, S, rowptr, dinv, esorted, E, N, G, NB1);

    k_gemm1<<<(N + 15) / 16, 256, 0, stream>>>(x, W1, dinv, hp1h, N);
    k_agg1<<<(unsigned)(((size_t)N * 64 + 255) / 256), 256, 0, stream>>>(
        rowptr, esorted, (const __half2*)hp1h, dinv, b1, W2, hp2, N);
    k_agg2<<<(unsigned)(((size_t)N * 8 + 255) / 256), 256, 0, stream>>>(
        rowptr, esorted, hp2, dinv, b2, out, N);
}